// Round 9
// baseline (760.278 us; speedup 1.0000x reference)
//
#include <hip/hip_runtime.h>
#include <hip/hip_bf16.h>

// ---------- types / helpers ----------
typedef __bf16 bf16x8 __attribute__((ext_vector_type(8)));
typedef float  f32x4  __attribute__((ext_vector_type(4)));

__device__ __forceinline__ ushort f2bf(float f) {
    unsigned u = __float_as_uint(f);
    u += 0x7FFF + ((u >> 16) & 1);      // RNE
    return (ushort)(u >> 16);
}

// DPP-based sum across 16-lane group (VALU only, no DS on the critical path)
template <int CTRL>
__device__ __forceinline__ float dppadd(float x) {
    int y = __builtin_amdgcn_update_dpp(0, __float_as_int(x), CTRL, 0xF, 0xF, true);
    return x + __int_as_float(y);
}
__device__ __forceinline__ float red16(float x) {
    x = dppadd<0xB1>(x);    // quad_perm [1,0,3,2]  : xor 1
    x = dppadd<0x4E>(x);    // quad_perm [2,3,0,1]  : xor 2
    x = dppadd<0x141>(x);   // row_half_mirror      : combine 4s within 8
    x = dppadd<0x140>(x);   // row_mirror           : combine 8s within 16
    return x;
}

// ---------- cast fp32 -> bf16 (x4 vectorized) ----------
__global__ void cast_bf16x4(const float4* __restrict__ x, ushort4* __restrict__ y, int n4) {
    int i = blockIdx.x * 256 + threadIdx.x;
    if (i < n4) {
        float4 v = x[i];
        y[i] = make_ushort4(f2bf(v.x), f2bf(v.y), f2bf(v.z), f2bf(v.w));
    }
}

// ---------- transpose + cast: W[K,N] fp32 -> Wt[N,K] bf16 ----------
__global__ __launch_bounds__(256) void transpose_cast(const float* __restrict__ W,
                                                      ushort* __restrict__ Wt,
                                                      int K, int N) {
    __shared__ float tile[32][33];
    int n0 = blockIdx.x * 32, k0 = blockIdx.y * 32;
    int tx = threadIdx.x & 31, ty = threadIdx.x >> 5;   // ty 0..7
#pragma unroll
    for (int i = 0; i < 32; i += 8)
        tile[ty + i][tx] = W[(size_t)(k0 + ty + i) * N + n0 + tx];
    __syncthreads();
#pragma unroll
    for (int i = 0; i < 32; i += 8)
        Wt[(size_t)(n0 + ty + i) * K + k0 + tx] = f2bf(tile[tx][ty + i]);
}

// ---------- tiny fp32 transpose for Wb/Wa: [2048,12] -> [12,2048] ----------
__global__ void wtrans_kernel(const float* __restrict__ Wb, const float* __restrict__ Wa,
                              float* __restrict__ WbT, float* __restrict__ WaT) {
    int i = blockIdx.x * 256 + threadIdx.x;   // 0..24575
    int hh = i >> 11, e = i & 2047;
    WbT[i] = Wb[(size_t)e * 12 + hh];
    WaT[i] = Wa[(size_t)e * 12 + hh];
}

// ---------- bf16 GEMM: C[M,N] = A[M,K] * Bt[N,K]^T, fp32 acc ----------
__global__ __launch_bounds__(256) void gemm_bt(const ushort* __restrict__ A,
                                               const ushort* __restrict__ Bt0,
                                               const ushort* __restrict__ Bt1,
                                               void* __restrict__ C0v,
                                               void* __restrict__ C1v,
                                               int M, int N, int K, int out_bf16) {
    const ushort* Bt = blockIdx.z ? Bt1 : Bt0;
    void* Cv = blockIdx.z ? C1v : C0v;
    __shared__ __align__(16) ushort As[128 * 32];
    __shared__ __align__(16) ushort Bs[128 * 32];
    const int tid = threadIdx.x;
    const int m0 = blockIdx.y * 128, n0 = blockIdx.x * 128;

    const int r0 = tid >> 2, cc = (tid & 3) * 8;
    const ushort* ga0 = A  + (size_t)(m0 + r0)      * K + cc;
    const ushort* ga1 = A  + (size_t)(m0 + r0 + 64) * K + cc;
    const ushort* gb0 = Bt + (size_t)(n0 + r0)      * K + cc;
    const ushort* gb1 = Bt + (size_t)(n0 + r0 + 64) * K + cc;
    const int la0 = r0 * 32 + cc, la1 = (r0 + 64) * 32 + cc;

    const int lane = tid & 63;
    const int wid = tid >> 6;
    const int wr = (wid >> 1) * 64, wc = (wid & 1) * 64;
    const int fr = lane & 15, koff = (lane >> 4) * 8;

    f32x4 acc[4][4] = {};
    for (int k0 = 0; k0 < K; k0 += 32) {
        uint4 va0 = *(const uint4*)(ga0 + k0);
        uint4 va1 = *(const uint4*)(ga1 + k0);
        uint4 vb0 = *(const uint4*)(gb0 + k0);
        uint4 vb1 = *(const uint4*)(gb1 + k0);
        __syncthreads();
        *(uint4*)&As[la0] = va0;
        *(uint4*)&As[la1] = va1;
        *(uint4*)&Bs[la0] = vb0;
        *(uint4*)&Bs[la1] = vb1;
        __syncthreads();
        bf16x8 af[4], bf[4];
#pragma unroll
        for (int i = 0; i < 4; ++i) {
            af[i] = *(const bf16x8*)&As[(wr + i * 16 + fr) * 32 + koff];
            bf[i] = *(const bf16x8*)&Bs[(wc + i * 16 + fr) * 32 + koff];
        }
#pragma unroll
        for (int i = 0; i < 4; ++i)
#pragma unroll
            for (int j = 0; j < 4; ++j)
                acc[i][j] = __builtin_amdgcn_mfma_f32_16x16x32_bf16(af[i], bf[j], acc[i][j], 0, 0, 0);
    }
    const int rbase = (lane >> 4) * 4;
    if (out_bf16) {
        ushort* C = (ushort*)Cv;
#pragma unroll
        for (int i = 0; i < 4; ++i)
#pragma unroll
            for (int j = 0; j < 4; ++j)
#pragma unroll
                for (int r = 0; r < 4; ++r)
                    C[(size_t)(m0 + wr + i * 16 + rbase + r) * N + n0 + wc + j * 16 + fr] = f2bf(acc[i][j][r]);
    } else {
        float* C = (float*)Cv;
#pragma unroll
        for (int i = 0; i < 4; ++i)
#pragma unroll
            for (int j = 0; j < 4; ++j)
#pragma unroll
                for (int r = 0; r < 4; ++r)
                    C[(size_t)(m0 + wr + i * 16 + rbase + r) * N + n0 + wc + j * 16 + fr] = acc[i][j][r];
    }
}

// ---------- beta / g projections (coalesced transposed weights) ----------
__global__ __launch_bounds__(256) void bg_kernel(const float* __restrict__ hs,
                                                 const float* __restrict__ WbT,
                                                 const float* __restrict__ WaT,
                                                 const float* __restrict__ A_log,
                                                 const float* __restrict__ dt_bias,
                                                 float* __restrict__ beta,
                                                 float* __restrict__ g) {
    __shared__ float xs[2048];
    int t = blockIdx.x;
    for (int i = threadIdx.x; i < 2048; i += 256) xs[i] = hs[(size_t)t * 2048 + i];
    __syncthreads();
    int w = threadIdx.x >> 6, l = threadIdx.x & 63;
#pragma unroll
    for (int i = 0; i < 6; ++i) {
        int d = w * 6 + i;          // 0..23
        int hh = d % 12;
        const float* W = ((d < 12) ? WbT : WaT) + (size_t)hh * 2048;
        float p = 0.f;
        for (int e = l; e < 2048; e += 64) p += xs[e] * W[e];
#pragma unroll
        for (int m = 32; m >= 1; m >>= 1) p += __shfl_xor(p, m, 64);
        if (l == 0) {
            if (d < 12) {
                beta[t * 12 + hh] = 1.f / (1.f + expf(-p));
            } else {
                float xg = p + dt_bias[hh];
                float sp = (xg > 15.f) ? xg : log1pf(expf(xg));
                g[t * 12 + hh] = -expf(A_log[hh]) * sp;
            }
        }
    }
}

// ---------- causal conv(K=4) + SiLU + l2norm for q/k (reads merged proj) ----------
__global__ void convqk_kernel(const float* __restrict__ proj,
                              const float* __restrict__ cwq, const float* __restrict__ cwk,
                              float* __restrict__ qout, float* __restrict__ kout) {
    int t = blockIdx.x, h = blockIdx.y, which = blockIdx.z;
    const float* x = proj + which * 1536;       // q at col 0, k at col 1536
    const float* cw = which ? cwk : cwq;
    float* out = which ? kout : qout;
    int c = threadIdx.x;                 // 0..127
    int ch = h * 128 + c;
    float4 w = *(const float4*)(cw + (size_t)ch * 4);
    float y = w.w * x[(size_t)t * 9216 + ch];
    if (t >= 1) y += w.z * x[(size_t)(t - 1) * 9216 + ch];
    if (t >= 2) y += w.y * x[(size_t)(t - 2) * 9216 + ch];
    if (t >= 3) y += w.x * x[(size_t)(t - 3) * 9216 + ch];
    y = y / (1.f + __expf(-y));          // silu
    float ss = y * y;
#pragma unroll
    for (int m = 32; m >= 1; m >>= 1) ss += __shfl_xor(ss, m, 64);
    __shared__ float red[2];
    if ((threadIdx.x & 63) == 0) red[threadIdx.x >> 6] = ss;
    __syncthreads();
    float tot = red[0] + red[1];
    out[((size_t)t * 12 + h) * 128 + c] = y * rsqrtf(tot + 1e-6f);
}

// ---------- causal conv(K=4) + SiLU for v (merged proj col 3072) ----------
__global__ void convv_kernel(const float* __restrict__ proj, const float* __restrict__ cwv,
                             float* __restrict__ vout) {
    int t = blockIdx.x, h = blockIdx.y;
    const float* x = proj + 3072;
    int c = threadIdx.x;                 // 0..255
    int ch = h * 256 + c;
    float4 w = *(const float4*)(cwv + (size_t)ch * 4);
    float y = w.w * x[(size_t)t * 9216 + ch];
    if (t >= 1) y += w.z * x[(size_t)(t - 1) * 9216 + ch];
    if (t >= 2) y += w.y * x[(size_t)(t - 2) * 9216 + ch];
    if (t >= 3) y += w.x * x[(size_t)(t - 3) * 9216 + ch];
    y = y / (1.f + __expf(-y));
    vout[((size_t)t * 12 + h) * 256 + c] = y;
}

// ---------- gated delta rule scan (v5: chunk=8 reg-staged LDS, conflict-free reads) ----------
// 3072 (head, dv) column recurrences; 16 lanes/column, 4 columns/wave, 768 one-wave
// blocks. Chunk=8 staging burst (32 VGPR - no spill, unlike v4's 64); element
// partition per lane = {l16*4..+3} U {64+l16*4..+3} so LDS reads are two b128s at
// 16B stride -> 2-way bank aliasing (free) instead of 4-way.
__global__ __launch_bounds__(64) void scan_kernel(const float* __restrict__ qn,
                                                  const float* __restrict__ kn,
                                                  const float* __restrict__ vv,
                                                  const float* __restrict__ gd,
                                                  const float* __restrict__ bt,
                                                  float* __restrict__ o) {
    const int b = blockIdx.x;
    const int h = b >> 6;
    const int quad = b & 63;
    const int tid = threadIdx.x;
    const int grp = tid >> 4;
    const int l16 = tid & 15;
    const int dv = quad * 4 + grp;

    __shared__ float kq[2][8][256];     // [t][0..127]=k row, [128..255]=q row
    __shared__ float vgb[2][8][8];      // [t][0..3]=v(4 cols), [4]=g, [5]=b

    const int sh = tid & 31;
    const float* srcA = (tid < 32 ? kn : qn) + h * 128 + sh * 4;  // +t*1536
    const float* vsrc = vv + h * 256 + quad * 4 + (tid & 3);      // +t*3072
    const int qoff = (tid >= 32) ? 128 : 0;
    float* op = o + h * 256 + dv;                                 // +t*3072

    float S0 = 0.f, S1 = 0.f, S2 = 0.f, S3 = 0.f, S4 = 0.f, S5 = 0.f, S6 = 0.f, S7 = 0.f;
    float4 kaC, kbC, qaC, qbC; float vC, gC, bC;
    float4 kaN, kbN, qaN, qbN; float vN, gN, bN;
    float4 stg[8]; float vstg, gbstg;

#define ISSUE_STAGE(TC) { \
    const int tc_ = (TC) < 1024 ? (TC) : 1016; \
    _Pragma("unroll") \
    for (int tt = 0; tt < 8; ++tt) \
        stg[tt] = *(const float4*)(srcA + (size_t)(tc_ + tt) * 1536); \
    vstg = 0.f; gbstg = 0.f; \
    if (tid < 32) vstg = vsrc[(size_t)(tc_ + (tid >> 2)) * 3072]; \
    else if (tid < 40) gbstg = gd[(size_t)(tc_ + (tid - 32)) * 12 + h]; \
    else if (tid < 48) gbstg = bt[(size_t)(tc_ + (tid - 40)) * 12 + h]; \
    __builtin_amdgcn_sched_barrier(0); /* pin burst issue before chunk compute */ }

#define WRITE_STAGE(P) { \
    _Pragma("unroll") \
    for (int tt = 0; tt < 8; ++tt) \
        *(float4*)&kq[P][tt][qoff + sh * 4] = stg[tt]; \
    if (tid < 32) vgb[P][tid >> 2][tid & 3] = vstg; \
    else if (tid < 40) vgb[P][tid - 32][4] = gbstg; \
    else if (tid < 48) vgb[P][tid - 40][5] = gbstg; }

#define LDS_READ_C(P, T) { \
    kaC = *(const float4*)&kq[P][T][l16 * 4]; \
    kbC = *(const float4*)&kq[P][T][64 + l16 * 4]; \
    qaC = *(const float4*)&kq[P][T][128 + l16 * 4]; \
    qbC = *(const float4*)&kq[P][T][192 + l16 * 4]; \
    vC = vgb[P][T][grp]; gC = vgb[P][T][4]; bC = vgb[P][T][5]; }

#define LDS_READ_N(P, T) { \
    kaN = *(const float4*)&kq[P][T][l16 * 4]; \
    kbN = *(const float4*)&kq[P][T][64 + l16 * 4]; \
    qaN = *(const float4*)&kq[P][T][128 + l16 * 4]; \
    qbN = *(const float4*)&kq[P][T][192 + l16 * 4]; \
    vN = vgb[P][T][grp]; gN = vgb[P][T][4]; bN = vgb[P][T][5]; }

#define SHIFT() { kaC = kaN; kbC = kbN; qaC = qaN; qbC = qbN; vC = vN; gC = gN; bC = bN; }

#define STEP(TGLOB) { \
    float d_ = __expf(gC); \
    float p01 = kaC.x * S0 + kaC.y * S1, p23 = kaC.z * S2 + kaC.w * S3; \
    float p45 = kbC.x * S4 + kbC.y * S5, p67 = kbC.z * S6 + kbC.w * S7; \
    float p_ = red16((p01 + p23) + (p45 + p67)); \
    float delta = (vC - d_ * p_) * bC; \
    S0 = d_ * S0 + kaC.x * delta; S1 = d_ * S1 + kaC.y * delta; \
    S2 = d_ * S2 + kaC.z * delta; S3 = d_ * S3 + kaC.w * delta; \
    S4 = d_ * S4 + kbC.x * delta; S5 = d_ * S5 + kbC.y * delta; \
    S6 = d_ * S6 + kbC.z * delta; S7 = d_ * S7 + kbC.w * delta; \
    float o01 = qaC.x * S0 + qaC.y * S1, o23 = qaC.z * S2 + qaC.w * S3; \
    float o45 = qbC.x * S4 + qbC.y * S5, o67 = qbC.z * S6 + qbC.w * S7; \
    float oo = red16((o01 + o23) + (o45 + o67)); \
    if (l16 == 0) op[(size_t)(TGLOB) * 3072] = oo; }

    ISSUE_STAGE(0)
    WRITE_STAGE(0)
    __syncthreads();
    LDS_READ_C(0, 0)

    for (int c = 0; c < 128; ++c) {
        const int p = c & 1;
        ISSUE_STAGE((c + 1) * 8)            // burst for next chunk (covered by compute)
#pragma unroll
        for (int t = 0; t < 8; ++t) {
            if (t < 7) { LDS_READ_N(p, t + 1) }
            STEP(c * 8 + t)
            if (t < 7) { SHIFT() }
        }
        __syncthreads();
        WRITE_STAGE(p ^ 1)
        __syncthreads();
        LDS_READ_C(p ^ 1, 0)
    }
#undef ISSUE_STAGE
#undef WRITE_STAGE
#undef LDS_READ_C
#undef LDS_READ_N
#undef SHIFT
#undef STEP
}

// ---------- RMSNorm * norm_w * silu(gate), bf16 out (gate from merged proj col 6144) ----------
__global__ __launch_bounds__(256) void normgate_kernel(const float* __restrict__ o,
                                                       const float* __restrict__ proj,
                                                       const float* __restrict__ norm_w,
                                                       ushort* __restrict__ on) {
    int t = blockIdx.x, h = blockIdx.y;
    int c = threadIdx.x;                 // 0..255
    float val = o[((size_t)t * 12 + h) * 256 + c];
    float ss = val * val;
#pragma unroll
    for (int m = 32; m >= 1; m >>= 1) ss += __shfl_xor(ss, m, 64);
    __shared__ float red[4];
    if ((threadIdx.x & 63) == 0) red[threadIdx.x >> 6] = ss;
    __syncthreads();
    float tot = red[0] + red[1] + red[2] + red[3];
    float rstd = rsqrtf(tot * (1.f / 256.f) + 1e-5f);
    float gg = proj[(size_t)t * 9216 + 6144 + h * 256 + c];
    float res = val * rstd * norm_w[c] * (gg / (1.f + __expf(-gg)));
    on[(size_t)t * 3072 + h * 256 + c] = f2bf(res);
}

// ---------- launch ----------
extern "C" void kernel_launch(void* const* d_in, const int* in_sizes, int n_in,
                              void* d_out, int out_size, void* d_ws, size_t ws_size,
                              hipStream_t stream) {
    const float* hs   = (const float*)d_in[0];   // [1024,2048]
    const float* Wq   = (const float*)d_in[1];   // [2048,1536]
    const float* Wk   = (const float*)d_in[2];
    const float* Wv   = (const float*)d_in[3];   // [2048,3072]
    const float* Wb   = (const float*)d_in[4];   // [2048,12]
    const float* Wa   = (const float*)d_in[5];
    const float* Wg   = (const float*)d_in[6];   // [2048,3072]
    const float* Wo   = (const float*)d_in[7];   // [3072,2048]
    const float* cwq  = (const float*)d_in[8];   // [1536,4]
    const float* cwk  = (const float*)d_in[9];
    const float* cwv  = (const float*)d_in[10];  // [3072,4]
    const float* A_log   = (const float*)d_in[11];
    const float* dt_bias = (const float*)d_in[12];
    const float* norm_w  = (const float*)d_in[13];
    float* out = (float*)d_out;                  // [1024,2048] fp32

    char* w = (char*)d_ws;
    auto alloc = [&](size_t bytes) { char* p = w; w += (bytes + 255) & ~(size_t)255; return p; };
    ushort* hs_bf   = (ushort*)alloc(1024 * 2048 * 2);
    ushort* WqkvgT  = (ushort*)alloc((size_t)9216 * 2048 * 2);  // [q|k|v|g] rows
    ushort* WoT     = (ushort*)alloc((size_t)2048 * 3072 * 2);
    float* proj     = (float*)alloc((size_t)1024 * 9216 * 4);   // merged projections
    float* qn       = (float*)alloc((size_t)1024 * 1536 * 4);
    float* kn       = (float*)alloc((size_t)1024 * 1536 * 4);
    float* vn       = (float*)alloc((size_t)1024 * 3072 * 4);
    float* gdec     = (float*)alloc(1024 * 12 * 4);
    float* betab    = (float*)alloc(1024 * 12 * 4);
    float* ob       = (float*)alloc((size_t)1024 * 3072 * 4);
    ushort* onb     = (ushort*)alloc((size_t)1024 * 3072 * 2);
    float* WbT      = (float*)alloc(12 * 2048 * 4);
    float* WaT      = (float*)alloc(12 * 2048 * 4);
    (void)ws_size; (void)n_in; (void)in_sizes; (void)out_size;

    // casts / transposes (concatenated weight: q@0, k@1536, v@3072, g@6144)
    cast_bf16x4<<<2048, 256, 0, stream>>>((const float4*)hs, (ushort4*)hs_bf, 1024 * 2048 / 4);
    transpose_cast<<<dim3(48, 64), 256, 0, stream>>>(Wq, WqkvgT, 2048, 1536);
    transpose_cast<<<dim3(48, 64), 256, 0, stream>>>(Wk, WqkvgT + (size_t)1536 * 2048, 2048, 1536);
    transpose_cast<<<dim3(96, 64), 256, 0, stream>>>(Wv, WqkvgT + (size_t)3072 * 2048, 2048, 3072);
    transpose_cast<<<dim3(96, 64), 256, 0, stream>>>(Wg, WqkvgT + (size_t)6144 * 2048, 2048, 3072);
    transpose_cast<<<dim3(64, 96), 256, 0, stream>>>(Wo, WoT, 3072, 2048);
    wtrans_kernel<<<96, 256, 0, stream>>>(Wb, Wa, WbT, WaT);

    // merged q/k/v/g projection: [1024,2048] x [2048,9216]
    gemm_bt<<<dim3(72, 8, 1), 256, 0, stream>>>(hs_bf, WqkvgT, WqkvgT, proj, proj, 1024, 9216, 2048, 0);
    bg_kernel<<<1024, 256, 0, stream>>>(hs, WbT, WaT, A_log, dt_bias, betab, gdec);

    // conv + silu (+ l2norm for q/k)
    convqk_kernel<<<dim3(1024, 12, 2), 128, 0, stream>>>(proj, cwq, cwk, qn, kn);
    convv_kernel<<<dim3(1024, 12), 256, 0, stream>>>(proj, cwv, vn);

    // gated delta rule
    scan_kernel<<<768, 64, 0, stream>>>(qn, kn, vn, gdec, betab, ob);

    // norm + gate -> bf16 (A operand of final GEMM)
    normgate_kernel<<<dim3(1024, 12), 256, 0, stream>>>(ob, proj, norm_w, onb);

    // output projection -> fp32 d_out
    gemm_bt<<<dim3(16, 8, 1), 256, 0, stream>>>(onb, WoT, WoT, (void*)out, (void*)out, 1024, 2048, 3072, 0);
}